// Round 18
// baseline (3170.004 us; speedup 1.0000x reference)
//
#include <hip/hip_runtime.h>

// ---------------------------------------------------------------------------
// GraphTransformer R18: R17 + edgefuse: 4 edges in flight (8 outstanding
// loads/lane) + last-block iz reduction folded in (reduceIz launches gone,
// ticket + threadfence, fixed-order tree -> deterministic).
// ---------------------------------------------------------------------------

typedef __attribute__((ext_vector_type(8))) short bf16x8;
typedef __attribute__((ext_vector_type(4))) float f32x4;

__device__ __forceinline__ unsigned short f2bf_rne(float f) {
  unsigned int u = __builtin_bit_cast(unsigned int, f);
  u = (u + 0x7fffu + ((u >> 16) & 1u)) >> 16;
  return (unsigned short)u;
}
__device__ __forceinline__ unsigned int pack2bf(float a, float b) {
  return (unsigned int)f2bf_rne(a) | ((unsigned int)f2bf_rne(b) << 16);
}
__device__ __forceinline__ float bflo(unsigned int w) {
  return __builtin_bit_cast(float, w << 16);
}
__device__ __forceinline__ float bfhi(unsigned int w) {
  return __builtin_bit_cast(float, w & 0xffff0000u);
}
__device__ __forceinline__ float dot8(uint4 a, uint4 b) {
  float s = bflo(a.x) * bflo(b.x) + bfhi(a.x) * bfhi(b.x);
  s += bflo(a.y) * bflo(b.y) + bfhi(a.y) * bfhi(b.y);
  s += bflo(a.z) * bflo(b.z) + bfhi(a.z) * bfhi(b.z);
  s += bflo(a.w) * bflo(b.w) + bfhi(a.w) * bfhi(b.w);
  return s;
}
__device__ __forceinline__ void gload16(const void* g, void* l) {
  __builtin_amdgcn_global_load_lds(
      (const __attribute__((address_space(1))) void*)g,
      (__attribute__((address_space(3))) void*)l, 16, 0, 0);
}

// ---------------- MFMA GEMM: Y = op(A[M,K] @ W + bias) (+R) ----------------
template<bool RELU, bool RES, bool OUTF, bool OUTB, bool AF32, bool SCALE>
__global__ __launch_bounds__(256)
void mgemm_k(const void* __restrict__ Ain,
             const unsigned short* __restrict__ Bt,
             const float* __restrict__ bias, const float* __restrict__ R,
             const float* __restrict__ scl,
             float* __restrict__ Yf, unsigned short* __restrict__ Yb,
             int M, int K, int N) {
  __shared__ __align__(16) char smem[32768];   // A 16KB | B 16KB
  const int t = threadIdx.x;
  const int l = t & 63;
  const int w = t >> 6, wm = w >> 1, wn = w & 1;
  const int row0 = blockIdx.x * 64;
  const int col0 = blockIdx.y * 64;

  f32x4 acc[2][2];
#pragma unroll
  for (int m = 0; m < 2; m++)
#pragma unroll
    for (int n = 0; n < 2; n++)
#pragma unroll
      for (int r = 0; r < 4; r++) acc[m][n][r] = 0.f;

  for (int kc = 0; kc < K; kc += 128) {
    if (kc) __syncthreads();
#pragma unroll
    for (int j = 0; j < 4; j++) {
      int id = j * 256 + t;
      int row = id >> 4, c16 = id & 15;
      int gr = row0 + row; if (gr >= M) gr = M - 1;
      if (AF32) {
        const float* ap = (const float*)Ain + (size_t)gr * K + kc + c16 * 8;
        float4 f0 = *(const float4*)ap;
        float4 f1 = *(const float4*)(ap + 4);
        float s = SCALE ? scl[(kc + c16 * 8) >> 5] : 1.f;
        uint4 val;
        val.x = pack2bf(f0.x * s, f0.y * s); val.y = pack2bf(f0.z * s, f0.w * s);
        val.z = pack2bf(f1.x * s, f1.y * s); val.w = pack2bf(f1.z * s, f1.w * s);
        *(uint4*)(smem + row * 256 + ((c16 * 16) ^ ((row & 7) << 4))) = val;
      } else {
        int sc16 = c16 ^ (row & 7);      // source-side swizzle
        const unsigned short* gp = (const unsigned short*)Ain + (size_t)gr * K + kc + sc16 * 8;
        gload16(gp, smem + (j * 256 + w * 64) * 16);
      }
    }
#pragma unroll
    for (int j = 0; j < 4; j++) {
      int id = j * 256 + t;
      int row = id >> 4, c16 = id & 15;
      int sc16 = c16 ^ (row & 7);        // source-side swizzle
      const unsigned short* gp = Bt + (size_t)(col0 + row) * K + kc + sc16 * 8;
      gload16(gp, smem + 16384 + (j * 256 + w * 64) * 16);
    }
    __syncthreads();

#pragma unroll
    for (int ks = 0; ks < 4; ks++) {
      const int bofs = ks * 64 + (l >> 4) * 16;
      bf16x8 a[2], b[2];
#pragma unroll
      for (int m = 0; m < 2; m++) {
        int r = wm * 32 + m * 16 + (l & 15);
        a[m] = *(const bf16x8*)(smem + r * 256 + (bofs ^ ((r & 7) << 4)));
      }
#pragma unroll
      for (int n = 0; n < 2; n++) {
        int r = wn * 32 + n * 16 + (l & 15);
        b[n] = *(const bf16x8*)(smem + 16384 + r * 256 + (bofs ^ ((r & 7) << 4)));
      }
#pragma unroll
      for (int m = 0; m < 2; m++)
#pragma unroll
        for (int n = 0; n < 2; n++)
          acc[m][n] = __builtin_amdgcn_mfma_f32_16x16x32_bf16(a[m], b[n], acc[m][n], 0, 0, 0);
    }
  }

  const int rbase = row0 + wm * 32 + ((l >> 4) << 2);
  const int cl = l & 15;
#pragma unroll
  for (int n = 0; n < 2; n++) {
    int col = col0 + wn * 32 + n * 16 + cl;
    float bb = bias[col];
#pragma unroll
    for (int m = 0; m < 2; m++) {
      int rtile = rbase + m * 16;
#pragma unroll
      for (int r = 0; r < 4; r++) {
        int row = rtile + r;
        if (row < M) {
          float o = acc[m][n][r] + bb;
          if (RES) o += R[(size_t)row * N + col];
          if (RELU) o = fmaxf(o, 0.f);
          if (OUTF) Yf[(size_t)row * N + col] = o;
          if (OUTB) Yb[(size_t)row * N + col] = f2bf_rne(o);
        }
      }
    }
  }
}

// ---------------- fused weight prep: transposes + bias concat + ticket -----
__global__ __launch_bounds__(256)
void prep_k(const float* __restrict__ Wi, const float* __restrict__ Wq,
            const float* __restrict__ Wk, const float* __restrict__ Wv,
            const float* __restrict__ Wo, const float* __restrict__ W1,
            const float* __restrict__ W2, const float* __restrict__ bq,
            const float* __restrict__ bk, const float* __restrict__ bv,
            unsigned short* __restrict__ WiT, unsigned short* __restrict__ WqkvT,
            unsigned short* __restrict__ WoT, unsigned short* __restrict__ W1T,
            unsigned short* __restrict__ W2T, float* __restrict__ bqkv,
            unsigned int* __restrict__ ticket) {
  if (blockIdx.x == 0 && threadIdx.x == 0) *ticket = 0;
  int o = blockIdx.x * 256 + threadIdx.x;
  if (o < 16384) {                         // Wi
    int n = o >> 7, k = o & 127;
    WiT[o] = f2bf_rne(Wi[k * 128 + n]);
    return;
  }
  o -= 16384;
  if (o < 98304) {                         // Wq|Wk|Wv, 2 layers each 128x128
    int seg = o >> 15; int r = o & 32767;
    int l = r >> 14; int rr = r & 16383;
    int n = rr >> 7, k = rr & 127;
    const float* W = (seg == 0) ? Wq : (seg == 1) ? Wk : Wv;
    WqkvT[(size_t)l * 49152 + seg * 16384 + n * 128 + k] =
        f2bf_rne(W[(size_t)l * 16384 + k * 128 + n]);
    return;
  }
  o -= 98304;
  if (o < 32768) {                         // Wo
    int l = o >> 14; int rr = o & 16383;
    int n = rr >> 7, k = rr & 127;
    WoT[(size_t)l * 16384 + n * 128 + k] = f2bf_rne(Wo[(size_t)l * 16384 + k * 128 + n]);
    return;
  }
  o -= 32768;
  if (o < 65536) {                         // W1: K=128,N=256
    int l = o >> 15; int rr = o & 32767;
    int n = rr >> 7, k = rr & 127;
    W1T[(size_t)l * 32768 + n * 128 + k] = f2bf_rne(W1[(size_t)l * 32768 + k * 256 + n]);
    return;
  }
  o -= 65536;
  if (o < 65536) {                         // W2: K=256,N=128
    int l = o >> 15; int rr = o & 32767;
    int n = rr >> 8, k = rr & 255;
    W2T[(size_t)l * 32768 + n * 256 + k] = f2bf_rne(W2[(size_t)l * 32768 + k * 128 + n]);
    return;
  }
  o -= 65536;
  if (o < 768) {                           // bqkv concat
    int l = o / 384, c = o - l * 384;
    float v = (c < 128) ? bq[l * 128 + c] : (c < 256) ? bk[l * 128 + c - 128] : bv[l * 128 + c - 256];
    bqkv[o] = v;
  }
}

// ---------------- radix sort: 2 passes x 8-bit, stable + deterministic -----
__global__ __launch_bounds__(256)
void rs_hist8_k(const int* __restrict__ key, int* __restrict__ gh,
                int E, int shift, int nblk) {
  __shared__ int h[256];
  int t = threadIdx.x, b = blockIdx.x;
  h[t] = 0;
  __syncthreads();
#pragma unroll
  for (int j = 0; j < 8; j++) {
    int i = b * 2048 + j * 256 + t;
    if (i < E) atomicAdd(&h[(key[i] >> shift) & 255], 1);
  }
  __syncthreads();
  gh[t * nblk + b] = h[t];
}

__global__ __launch_bounds__(256)
void scanA_k(const int* __restrict__ a, int* __restrict__ bsum, int n) {
  __shared__ int sm[256];
  int b = blockIdx.x, t = threadIdx.x;
  int base = b * 2048 + t * 8;
  int s = 0;
#pragma unroll
  for (int j = 0; j < 8; j++) {
    int i = base + j;
    if (i < n) s += a[i];
  }
  sm[t] = s; __syncthreads();
  for (int d = 128; d >= 1; d >>= 1) {
    if (t < d) sm[t] += sm[t + d];
    __syncthreads();
  }
  if (t == 0) bsum[b] = sm[0];
}

// scanC with fused block-base computation (bsum holds RAW block sums)
__global__ __launch_bounds__(256)
void scanC_k(int* __restrict__ a, const int* __restrict__ bsum, int n) {
  __shared__ int sm[256];
  __shared__ int blockbase;
  int b = blockIdx.x, t = threadIdx.x;
  if (t == 0) {
    int acc = 0;
    for (int b2 = 0; b2 < b; b2++) acc += bsum[b2];
    blockbase = acc;
  }
  int base = b * 2048 + t * 8;
  int vals[8];
  int s = 0;
#pragma unroll
  for (int j = 0; j < 8; j++) {
    int i = base + j;
    vals[j] = (i < n) ? a[i] : 0;
    s += vals[j];
  }
  sm[t] = s; __syncthreads();
  for (int d = 1; d < 256; d <<= 1) {
    int v = (t >= d) ? sm[t - d] : 0;
    __syncthreads();
    sm[t] += v;
    __syncthreads();
  }
  int run = blockbase + sm[t] - s;
#pragma unroll
  for (int j = 0; j < 8; j++) {
    int i = base + j;
    if (i < n) { a[i] = run; run += vals[j]; }
  }
}

__global__ __launch_bounds__(256)
void rs_scatter8_k(const int* __restrict__ keyIn, const int* __restrict__ payIn,
                   int* __restrict__ keyOut, int* __restrict__ payOut,
                   const int* __restrict__ gh, int E, int shift, int nblk) {
  __shared__ int base[256];
  __shared__ int wcnt[4][256];
  int t = threadIdx.x, b = blockIdx.x;
  int w = t >> 6, ln = t & 63;
  unsigned long long lmask = (1ull << ln) - 1ull;
  base[t] = gh[t * nblk + b];
  wcnt[0][t] = 0; wcnt[1][t] = 0; wcnt[2][t] = 0; wcnt[3][t] = 0;
  __syncthreads();
  for (int j = 0; j < 8; j++) {
    int i = b * 2048 + j * 256 + t;
    bool valid = i < E;
    int kv = valid ? keyIn[i] : 0;
    int d = (kv >> shift) & 255;
    if (valid) atomicAdd(&wcnt[w][d], 1);
    unsigned long long mm = __ballot(valid);
#pragma unroll
    for (int bit = 0; bit < 8; bit++) {
      unsigned long long bb = __ballot((d >> bit) & 1);
      mm &= ((d >> bit) & 1) ? bb : ~bb;
    }
    int myrank = __popcll(mm & lmask);
    __syncthreads();
    if (valid) {
      int wbase = 0;
      for (int w2 = 0; w2 < w; w2++) wbase += wcnt[w2][d];
      int pos = base[d] + wbase + myrank;
      keyOut[pos] = kv;
      payOut[pos] = payIn ? payIn[i] : i;
    }
    __syncthreads();
    base[t] += wcnt[0][t] + wcnt[1][t] + wcnt[2][t] + wcnt[3][t];
    wcnt[0][t] = 0; wcnt[1][t] = 0; wcnt[2][t] = 0; wcnt[3][t] = 0;
    __syncthreads();
  }
}

// merged: srcP gather + CSR bounds from sorted keys
__global__ __launch_bounds__(256)
void boundsmeta_k(const int* __restrict__ key, const int* __restrict__ pay,
                  const int* __restrict__ src, int* __restrict__ off,
                  int* __restrict__ srcP, int E, int N) {
  int i = blockIdx.x * 256 + threadIdx.x;
  if (i >= E) return;
  srcP[i] = src[pay[i]];
  int k1 = key[i];
  int k0 = (i == 0) ? -1 : key[i - 1];
  for (int d = k0 + 1; d <= k1; d++) off[d] = i;
  if (i == E - 1) {
    for (int d = k1 + 1; d <= N; d++) off[d] = E;
  }
}

// ---------------- fused edge pass: exp2(q.k) -> unnorm agg + psum + iz -----
// wave = node; 4 edges x 16 lanes; lane q owns dims [q*8, q*8+8) (16B).
// 4 edges in flight (8 outstanding uint4 loads/lane). Last block reduces
// psum -> iz (fixed-order tree, deterministic) and resets ticket.
__global__ __launch_bounds__(256)
void edgefuse_k(const unsigned short* __restrict__ QKV,
                const int* __restrict__ srcP, const int* __restrict__ off,
                float* __restrict__ AGu, float* __restrict__ psum,
                float* __restrict__ iz, unsigned int* __restrict__ ticket,
                int Nn, float kscale) {
  __shared__ float ps[4][4];
  int t = threadIdx.x;
  int wv = t >> 6, l = t & 63;
  int p = l >> 4;                  // edge parity 0..3
  int q = l & 15;                  // 16B chunk; dims [q*8, q*8+8)
  int h = q >> 2;                  // head
  int node = blockIdx.x * 4 + wv;
  float a0 = 0.f, a1 = 0.f, a2 = 0.f, a3 = 0.f;
  float a4 = 0.f, a5 = 0.f, a6 = 0.f, a7 = 0.f;
  float pacc = 0.f;
  if (node < Nn) {
    uint4 qv = *(const uint4*)(QKV + (size_t)node * 384 + q * 8);
    int lo = off[node], hi = off[node + 1];
    int i = lo + p;
    for (; i + 12 < hi; i += 16) {
      int s0 = srcP[i], s1 = srcP[i + 4], s2 = srcP[i + 8], s3 = srcP[i + 12];
      const unsigned short* r0 = QKV + (size_t)s0 * 384;
      const unsigned short* r1 = QKV + (size_t)s1 * 384;
      const unsigned short* r2 = QKV + (size_t)s2 * 384;
      const unsigned short* r3 = QKV + (size_t)s3 * 384;
      uint4 k0 = *(const uint4*)(r0 + 128 + q * 8);
      uint4 k1 = *(const uint4*)(r1 + 128 + q * 8);
      uint4 k2 = *(const uint4*)(r2 + 128 + q * 8);
      uint4 k3 = *(const uint4*)(r3 + 128 + q * 8);
      uint4 v0 = *(const uint4*)(r0 + 256 + q * 8);
      uint4 v1 = *(const uint4*)(r1 + 256 + q * 8);
      uint4 v2 = *(const uint4*)(r2 + 256 + q * 8);
      uint4 v3 = *(const uint4*)(r3 + 256 + q * 8);
      float d0 = dot8(qv, k0);
      float d1 = dot8(qv, k1);
      float d2 = dot8(qv, k2);
      float d3 = dot8(qv, k3);
      d0 += __shfl_xor(d0, 1); d0 += __shfl_xor(d0, 2);
      d1 += __shfl_xor(d1, 1); d1 += __shfl_xor(d1, 2);
      d2 += __shfl_xor(d2, 1); d2 += __shfl_xor(d2, 2);
      d3 += __shfl_xor(d3, 1); d3 += __shfl_xor(d3, 2);
      float c0 = __builtin_amdgcn_exp2f(d0 * kscale);
      float c1 = __builtin_amdgcn_exp2f(d1 * kscale);
      float c2 = __builtin_amdgcn_exp2f(d2 * kscale);
      float c3 = __builtin_amdgcn_exp2f(d3 * kscale);
      if ((q & 3) == 0) pacc += (c0 + c1) + (c2 + c3);
      a0 = fmaf(c0, bflo(v0.x), a0); a1 = fmaf(c0, bfhi(v0.x), a1);
      a2 = fmaf(c0, bflo(v0.y), a2); a3 = fmaf(c0, bfhi(v0.y), a3);
      a4 = fmaf(c0, bflo(v0.z), a4); a5 = fmaf(c0, bfhi(v0.z), a5);
      a6 = fmaf(c0, bflo(v0.w), a6); a7 = fmaf(c0, bfhi(v0.w), a7);
      a0 = fmaf(c1, bflo(v1.x), a0); a1 = fmaf(c1, bfhi(v1.x), a1);
      a2 = fmaf(c1, bflo(v1.y), a2); a3 = fmaf(c1, bfhi(v1.y), a3);
      a4 = fmaf(c1, bflo(v1.z), a4); a5 = fmaf(c1, bfhi(v1.z), a5);
      a6 = fmaf(c1, bflo(v1.w), a6); a7 = fmaf(c1, bfhi(v1.w), a7);
      a0 = fmaf(c2, bflo(v2.x), a0); a1 = fmaf(c2, bfhi(v2.x), a1);
      a2 = fmaf(c2, bflo(v2.y), a2); a3 = fmaf(c2, bfhi(v2.y), a3);
      a4 = fmaf(c2, bflo(v2.z), a4); a5 = fmaf(c2, bfhi(v2.z), a5);
      a6 = fmaf(c2, bflo(v2.w), a6); a7 = fmaf(c2, bfhi(v2.w), a7);
      a0 = fmaf(c3, bflo(v3.x), a0); a1 = fmaf(c3, bfhi(v3.x), a1);
      a2 = fmaf(c3, bflo(v3.y), a2); a3 = fmaf(c3, bfhi(v3.y), a3);
      a4 = fmaf(c3, bflo(v3.z), a4); a5 = fmaf(c3, bfhi(v3.z), a5);
      a6 = fmaf(c3, bflo(v3.w), a6); a7 = fmaf(c3, bfhi(v3.w), a7);
    }
    for (; i < hi; i += 4) {
      int s = srcP[i];
      const unsigned short* r = QKV + (size_t)s * 384;
      uint4 kf = *(const uint4*)(r + 128 + q * 8);
      uint4 vf = *(const uint4*)(r + 256 + q * 8);
      float d = dot8(qv, kf);
      d += __shfl_xor(d, 1); d += __shfl_xor(d, 2);
      float c = __builtin_amdgcn_exp2f(d * kscale);
      if ((q & 3) == 0) pacc += c;
      a0 = fmaf(c, bflo(vf.x), a0); a1 = fmaf(c, bfhi(vf.x), a1);
      a2 = fmaf(c, bflo(vf.y), a2); a3 = fmaf(c, bfhi(vf.y), a3);
      a4 = fmaf(c, bflo(vf.z), a4); a5 = fmaf(c, bfhi(vf.z), a5);
      a6 = fmaf(c, bflo(vf.w), a6); a7 = fmaf(c, bfhi(vf.w), a7);
    }
  }
  a0 += __shfl_down(a0, 32); a0 += __shfl_down(a0, 16);
  a1 += __shfl_down(a1, 32); a1 += __shfl_down(a1, 16);
  a2 += __shfl_down(a2, 32); a2 += __shfl_down(a2, 16);
  a3 += __shfl_down(a3, 32); a3 += __shfl_down(a3, 16);
  a4 += __shfl_down(a4, 32); a4 += __shfl_down(a4, 16);
  a5 += __shfl_down(a5, 32); a5 += __shfl_down(a5, 16);
  a6 += __shfl_down(a6, 32); a6 += __shfl_down(a6, 16);
  a7 += __shfl_down(a7, 32); a7 += __shfl_down(a7, 16);
  pacc += __shfl_down(pacc, 32); pacc += __shfl_down(pacc, 16);
  if (p == 0 && (q & 3) == 0) ps[wv][h] = pacc;
  __syncthreads();
  if (t < 4) psum[(size_t)t * gridDim.x + blockIdx.x] =
      ps[0][t] + ps[1][t] + ps[2][t] + ps[3][t];
  if (node < Nn && p == 0) {
    float* op = AGu + (size_t)node * 128 + q * 8;
    *(float4*)op = make_float4(a0, a1, a2, a3);
    *(float4*)(op + 4) = make_float4(a4, a5, a6, a7);
  }

  // ---- last-block iz reduction (deterministic fixed-order tree) ----
  __threadfence();
  __shared__ int lastFlag;
  if (t == 0) {
    unsigned int c = atomicAdd(ticket, 1u);
    lastFlag = (c == gridDim.x - 1) ? 1 : 0;
  }
  __syncthreads();
  if (lastFlag) {
    __shared__ float sm2[256];
    int nb = gridDim.x;
    for (int h2 = 0; h2 < 4; h2++) {
      float a = 0.f;
      for (int j = t; j < nb; j += 256) a += psum[(size_t)h2 * nb + j];
      sm2[t] = a; __syncthreads();
      for (int s = 128; s >= 1; s >>= 1) {
        if (t < s) sm2[t] += sm2[t + s];
        __syncthreads();
      }
      if (t == 0) iz[h2] = 1.0f / sm2[0];
      __syncthreads();
    }
    if (t == 0) *ticket = 0;
  }
}

// ---------------------------------------------------------------------------
extern "C" void kernel_launch(void* const* d_in, const int* in_sizes, int n_in,
                              void* d_out, int out_size, void* d_ws, size_t ws_size,
                              hipStream_t stream) {
  const float* x_in = (const float*)d_in[0];
  const int*   ei   = (const int*)d_in[1];
  const float* Wi = (const float*)d_in[2];
  const float* bi = (const float*)d_in[3];
  const float* Wq = (const float*)d_in[4];  const float* bq = (const float*)d_in[5];
  const float* Wk = (const float*)d_in[6];  const float* bk = (const float*)d_in[7];
  const float* Wv = (const float*)d_in[8];  const float* bv = (const float*)d_in[9];
  const float* Wo = (const float*)d_in[10]; const float* bo = (const float*)d_in[11];
  const float* W1 = (const float*)d_in[12]; const float* b1 = (const float*)d_in[13];
  const float* W2 = (const float*)d_in[14]; const float* b2 = (const float*)d_in[15];

  const int N = in_sizes[0] / 128;   // 50000
  const int E = in_sizes[1] / 2;     // 800000
  const int* src = ei;
  const int* dst = ei + E;

  char* w = (char*)d_ws;
  auto alloc = [&](size_t bytes) -> char* {
    char* p = w;
    w += (bytes + 255) & ~(size_t)255;
    return p;
  };
  float*          X    = (float*)alloc((size_t)N * 128 * 4);
  unsigned short* Xb   = (unsigned short*)alloc((size_t)N * 128 * 2);
  unsigned short* QKVb = (unsigned short*)alloc((size_t)N * 384 * 2);
  unsigned short* Hb   = QKVb;                 // FFN hidden aliases QKV (dead)
  float*          AGu  = (float*)alloc((size_t)N * 128 * 4);
  const int nbS = (N + 3) / 4;                 // 12500 edgefuse blocks
  float* psum = (float*)alloc((size_t)4 * nbS * 4);
  float* iz   = (float*)alloc(16);
  unsigned int* ticket = (unsigned int*)alloc(16);
  unsigned short* WiT   = (unsigned short*)alloc(16384 * 2);
  unsigned short* WqkvT = (unsigned short*)alloc((size_t)2 * 384 * 128 * 2);
  unsigned short* WoT   = (unsigned short*)alloc((size_t)2 * 16384 * 2);
  unsigned short* W1T   = (unsigned short*)alloc((size_t)2 * 32768 * 2);
  unsigned short* W2T   = (unsigned short*)alloc((size_t)2 * 32768 * 2);
  float* bqkv = (float*)alloc(768 * 4);
  int* off  = (int*)alloc((size_t)(N + 1) * 4);
  int* kA   = (int*)alloc((size_t)E * 4);
  int* pA   = (int*)alloc((size_t)E * 4);
  int* kB   = (int*)alloc((size_t)E * 4);
  int* pB   = (int*)alloc((size_t)E * 4);
  int* srcP = (int*)alloc((size_t)E * 4);
  const int nblk = (E + 2047) / 2048;       // 391
  const int ghn  = 256 * nblk;              // 100096
  int* gh   = (int*)alloc((size_t)ghn * 4);
  int* bsum = (int*)alloc(256 * 4);

  const float scale = 0.17677669529663687f;           // 1/sqrt(32)
  const float kscale = scale * 1.4426950408889634f;   // fold log2(e) for exp2
  dim3 blk(256);
  const int gx = (N + 63) / 64;              // 782
  dim3 gP(gx, 2), gQKV(gx, 6), gW1(gx, 4);
  const int gEe = (E + 255) / 256;
  const int nsb = (ghn + 2047) / 2048;       // 49

  // ---- CSR build: 2-pass 8-bit stable radix sort on dst ----
  rs_hist8_k<<<nblk, blk, 0, stream>>>(dst, gh, E, 0, nblk);
  scanA_k<<<nsb, blk, 0, stream>>>(gh, bsum, ghn);
  scanC_k<<<nsb, blk, 0, stream>>>(gh, bsum, ghn);
  rs_scatter8_k<<<nblk, blk, 0, stream>>>(dst, nullptr, kA, pA, gh, E, 0, nblk);
  rs_hist8_k<<<nblk, blk, 0, stream>>>(kA, gh, E, 8, nblk);
  scanA_k<<<nsb, blk, 0, stream>>>(gh, bsum, ghn);
  scanC_k<<<nsb, blk, 0, stream>>>(gh, bsum, ghn);
  rs_scatter8_k<<<nblk, blk, 0, stream>>>(kA, pA, kB, pB, gh, E, 8, nblk);
  boundsmeta_k<<<gEe, blk, 0, stream>>>(kB, pB, src, off, srcP, E, N);

  // ---- weight prep: single fused kernel (also zeroes ticket) ----
  prep_k<<<1091, blk, 0, stream>>>(Wi, Wq, Wk, Wv, Wo, W1, W2, bq, bk, bv,
                                   WiT, WqkvT, WoT, W1T, W2T, bqkv, ticket);

  // ---- input projection (f32 A, cast fused into staging) ----
  mgemm_k<false, false, true, true, true, false><<<gP, blk, 0, stream>>>(
      x_in, WiT, bi, nullptr, nullptr, X, Xb, N, 128, 128);

  for (int l = 0; l < 2; l++) {
    const float* bo_l = bo + l * 128;
    const float* b1_l = b1 + l * 256;
    const float* b2_l = b2 + l * 128;

    // QKV fused GEMM -> plain row-major [node][384] (Q|K|V)
    mgemm_k<false, false, false, true, false, false><<<gQKV, blk, 0, stream>>>(
        Xb, WqkvT + (size_t)l * 384 * 128, bqkv + l * 384, nullptr, nullptr,
        nullptr, QKVb, N, 128, 384);

    // fused edge pass: unnormalized agg + Z partials + last-block iz
    edgefuse_k<<<nbS, blk, 0, stream>>>(QKVb, srcP, off, AGu, psum, iz, ticket, N, kscale);

    // x = x + (AGu * iz) @ Wo + bo   (scale folded into A-staging)
    mgemm_k<false, true, true, true, true, true><<<gP, blk, 0, stream>>>(
        AGu, WoT + (size_t)l * 16384, bo_l, X, iz, X, Xb, N, 128, 128);
    // h = relu(x@W1 + b1)
    mgemm_k<true, false, false, true, false, false><<<gW1, blk, 0, stream>>>(
        Xb, W1T + (size_t)l * 32768, b1_l, nullptr, nullptr, nullptr, Hb, N, 128, 256);
    // x = x + h@W2 + b2
    if (l == 0) {
      mgemm_k<false, true, true, true, false, false><<<gP, blk, 0, stream>>>(
          Hb, W2T + (size_t)l * 32768, b2_l, X, nullptr, X, Xb, N, 256, 128);
    } else {
      mgemm_k<false, true, true, false, false, false><<<gP, blk, 0, stream>>>(
          Hb, W2T + (size_t)l * 32768, b2_l, X, nullptr, (float*)d_out, nullptr, N, 256, 128);
    }
  }
}

// Round 19
// 424.057 us; speedup vs baseline: 7.4754x; 7.4754x over previous
//
#include <hip/hip_runtime.h>

// ---------------------------------------------------------------------------
// GraphTransformer R19: R17 structure (separate reduceIz launch — R18's
// per-block device threadfence/ticket serialized all XCDs, ERRATA R18) but
// keeping the 4-edges-in-flight edgefuse body to isolate the ILP change.
// ---------------------------------------------------------------------------

typedef __attribute__((ext_vector_type(8))) short bf16x8;
typedef __attribute__((ext_vector_type(4))) float f32x4;

__device__ __forceinline__ unsigned short f2bf_rne(float f) {
  unsigned int u = __builtin_bit_cast(unsigned int, f);
  u = (u + 0x7fffu + ((u >> 16) & 1u)) >> 16;
  return (unsigned short)u;
}
__device__ __forceinline__ unsigned int pack2bf(float a, float b) {
  return (unsigned int)f2bf_rne(a) | ((unsigned int)f2bf_rne(b) << 16);
}
__device__ __forceinline__ float bflo(unsigned int w) {
  return __builtin_bit_cast(float, w << 16);
}
__device__ __forceinline__ float bfhi(unsigned int w) {
  return __builtin_bit_cast(float, w & 0xffff0000u);
}
__device__ __forceinline__ float dot8(uint4 a, uint4 b) {
  float s = bflo(a.x) * bflo(b.x) + bfhi(a.x) * bfhi(b.x);
  s += bflo(a.y) * bflo(b.y) + bfhi(a.y) * bfhi(b.y);
  s += bflo(a.z) * bflo(b.z) + bfhi(a.z) * bfhi(b.z);
  s += bflo(a.w) * bflo(b.w) + bfhi(a.w) * bfhi(b.w);
  return s;
}
__device__ __forceinline__ void gload16(const void* g, void* l) {
  __builtin_amdgcn_global_load_lds(
      (const __attribute__((address_space(1))) void*)g,
      (__attribute__((address_space(3))) void*)l, 16, 0, 0);
}

// ---------------- MFMA GEMM: Y = op(A[M,K] @ W + bias) (+R) ----------------
template<bool RELU, bool RES, bool OUTF, bool OUTB, bool AF32, bool SCALE>
__global__ __launch_bounds__(256)
void mgemm_k(const void* __restrict__ Ain,
             const unsigned short* __restrict__ Bt,
             const float* __restrict__ bias, const float* __restrict__ R,
             const float* __restrict__ scl,
             float* __restrict__ Yf, unsigned short* __restrict__ Yb,
             int M, int K, int N) {
  __shared__ __align__(16) char smem[32768];   // A 16KB | B 16KB
  const int t = threadIdx.x;
  const int l = t & 63;
  const int w = t >> 6, wm = w >> 1, wn = w & 1;
  const int row0 = blockIdx.x * 64;
  const int col0 = blockIdx.y * 64;

  f32x4 acc[2][2];
#pragma unroll
  for (int m = 0; m < 2; m++)
#pragma unroll
    for (int n = 0; n < 2; n++)
#pragma unroll
      for (int r = 0; r < 4; r++) acc[m][n][r] = 0.f;

  for (int kc = 0; kc < K; kc += 128) {
    if (kc) __syncthreads();
#pragma unroll
    for (int j = 0; j < 4; j++) {
      int id = j * 256 + t;
      int row = id >> 4, c16 = id & 15;
      int gr = row0 + row; if (gr >= M) gr = M - 1;
      if (AF32) {
        const float* ap = (const float*)Ain + (size_t)gr * K + kc + c16 * 8;
        float4 f0 = *(const float4*)ap;
        float4 f1 = *(const float4*)(ap + 4);
        float s = SCALE ? scl[(kc + c16 * 8) >> 5] : 1.f;
        uint4 val;
        val.x = pack2bf(f0.x * s, f0.y * s); val.y = pack2bf(f0.z * s, f0.w * s);
        val.z = pack2bf(f1.x * s, f1.y * s); val.w = pack2bf(f1.z * s, f1.w * s);
        *(uint4*)(smem + row * 256 + ((c16 * 16) ^ ((row & 7) << 4))) = val;
      } else {
        int sc16 = c16 ^ (row & 7);      // source-side swizzle
        const unsigned short* gp = (const unsigned short*)Ain + (size_t)gr * K + kc + sc16 * 8;
        gload16(gp, smem + (j * 256 + w * 64) * 16);
      }
    }
#pragma unroll
    for (int j = 0; j < 4; j++) {
      int id = j * 256 + t;
      int row = id >> 4, c16 = id & 15;
      int sc16 = c16 ^ (row & 7);        // source-side swizzle
      const unsigned short* gp = Bt + (size_t)(col0 + row) * K + kc + sc16 * 8;
      gload16(gp, smem + 16384 + (j * 256 + w * 64) * 16);
    }
    __syncthreads();

#pragma unroll
    for (int ks = 0; ks < 4; ks++) {
      const int bofs = ks * 64 + (l >> 4) * 16;
      bf16x8 a[2], b[2];
#pragma unroll
      for (int m = 0; m < 2; m++) {
        int r = wm * 32 + m * 16 + (l & 15);
        a[m] = *(const bf16x8*)(smem + r * 256 + (bofs ^ ((r & 7) << 4)));
      }
#pragma unroll
      for (int n = 0; n < 2; n++) {
        int r = wn * 32 + n * 16 + (l & 15);
        b[n] = *(const bf16x8*)(smem + 16384 + r * 256 + (bofs ^ ((r & 7) << 4)));
      }
#pragma unroll
      for (int m = 0; m < 2; m++)
#pragma unroll
        for (int n = 0; n < 2; n++)
          acc[m][n] = __builtin_amdgcn_mfma_f32_16x16x32_bf16(a[m], b[n], acc[m][n], 0, 0, 0);
    }
  }

  const int rbase = row0 + wm * 32 + ((l >> 4) << 2);
  const int cl = l & 15;
#pragma unroll
  for (int n = 0; n < 2; n++) {
    int col = col0 + wn * 32 + n * 16 + cl;
    float bb = bias[col];
#pragma unroll
    for (int m = 0; m < 2; m++) {
      int rtile = rbase + m * 16;
#pragma unroll
      for (int r = 0; r < 4; r++) {
        int row = rtile + r;
        if (row < M) {
          float o = acc[m][n][r] + bb;
          if (RES) o += R[(size_t)row * N + col];
          if (RELU) o = fmaxf(o, 0.f);
          if (OUTF) Yf[(size_t)row * N + col] = o;
          if (OUTB) Yb[(size_t)row * N + col] = f2bf_rne(o);
        }
      }
    }
  }
}

// ---------------- fused weight prep: all transposes + bias concat ----------
__global__ __launch_bounds__(256)
void prep_k(const float* __restrict__ Wi, const float* __restrict__ Wq,
            const float* __restrict__ Wk, const float* __restrict__ Wv,
            const float* __restrict__ Wo, const float* __restrict__ W1,
            const float* __restrict__ W2, const float* __restrict__ bq,
            const float* __restrict__ bk, const float* __restrict__ bv,
            unsigned short* __restrict__ WiT, unsigned short* __restrict__ WqkvT,
            unsigned short* __restrict__ WoT, unsigned short* __restrict__ W1T,
            unsigned short* __restrict__ W2T, float* __restrict__ bqkv) {
  int o = blockIdx.x * 256 + threadIdx.x;
  if (o < 16384) {                         // Wi
    int n = o >> 7, k = o & 127;
    WiT[o] = f2bf_rne(Wi[k * 128 + n]);
    return;
  }
  o -= 16384;
  if (o < 98304) {                         // Wq|Wk|Wv, 2 layers each 128x128
    int seg = o >> 15; int r = o & 32767;
    int l = r >> 14; int rr = r & 16383;
    int n = rr >> 7, k = rr & 127;
    const float* W = (seg == 0) ? Wq : (seg == 1) ? Wk : Wv;
    WqkvT[(size_t)l * 49152 + seg * 16384 + n * 128 + k] =
        f2bf_rne(W[(size_t)l * 16384 + k * 128 + n]);
    return;
  }
  o -= 98304;
  if (o < 32768) {                         // Wo
    int l = o >> 14; int rr = o & 16383;
    int n = rr >> 7, k = rr & 127;
    WoT[(size_t)l * 16384 + n * 128 + k] = f2bf_rne(Wo[(size_t)l * 16384 + k * 128 + n]);
    return;
  }
  o -= 32768;
  if (o < 65536) {                         // W1: K=128,N=256
    int l = o >> 15; int rr = o & 32767;
    int n = rr >> 7, k = rr & 127;
    W1T[(size_t)l * 32768 + n * 128 + k] = f2bf_rne(W1[(size_t)l * 32768 + k * 256 + n]);
    return;
  }
  o -= 65536;
  if (o < 65536) {                         // W2: K=256,N=128
    int l = o >> 15; int rr = o & 32767;
    int n = rr >> 8, k = rr & 255;
    W2T[(size_t)l * 32768 + n * 256 + k] = f2bf_rne(W2[(size_t)l * 32768 + k * 128 + n]);
    return;
  }
  o -= 65536;
  if (o < 768) {                           // bqkv concat
    int l = o / 384, c = o - l * 384;
    float v = (c < 128) ? bq[l * 128 + c] : (c < 256) ? bk[l * 128 + c - 128] : bv[l * 128 + c - 256];
    bqkv[o] = v;
  }
}

// ---------------- radix sort: 2 passes x 8-bit, stable + deterministic -----
__global__ __launch_bounds__(256)
void rs_hist8_k(const int* __restrict__ key, int* __restrict__ gh,
                int E, int shift, int nblk) {
  __shared__ int h[256];
  int t = threadIdx.x, b = blockIdx.x;
  h[t] = 0;
  __syncthreads();
#pragma unroll
  for (int j = 0; j < 8; j++) {
    int i = b * 2048 + j * 256 + t;
    if (i < E) atomicAdd(&h[(key[i] >> shift) & 255], 1);
  }
  __syncthreads();
  gh[t * nblk + b] = h[t];
}

__global__ __launch_bounds__(256)
void scanA_k(const int* __restrict__ a, int* __restrict__ bsum, int n) {
  __shared__ int sm[256];
  int b = blockIdx.x, t = threadIdx.x;
  int base = b * 2048 + t * 8;
  int s = 0;
#pragma unroll
  for (int j = 0; j < 8; j++) {
    int i = base + j;
    if (i < n) s += a[i];
  }
  sm[t] = s; __syncthreads();
  for (int d = 128; d >= 1; d >>= 1) {
    if (t < d) sm[t] += sm[t + d];
    __syncthreads();
  }
  if (t == 0) bsum[b] = sm[0];
}

// scanC with fused block-base computation (bsum holds RAW block sums)
__global__ __launch_bounds__(256)
void scanC_k(int* __restrict__ a, const int* __restrict__ bsum, int n) {
  __shared__ int sm[256];
  __shared__ int blockbase;
  int b = blockIdx.x, t = threadIdx.x;
  if (t == 0) {
    int acc = 0;
    for (int b2 = 0; b2 < b; b2++) acc += bsum[b2];
    blockbase = acc;
  }
  int base = b * 2048 + t * 8;
  int vals[8];
  int s = 0;
#pragma unroll
  for (int j = 0; j < 8; j++) {
    int i = base + j;
    vals[j] = (i < n) ? a[i] : 0;
    s += vals[j];
  }
  sm[t] = s; __syncthreads();
  for (int d = 1; d < 256; d <<= 1) {
    int v = (t >= d) ? sm[t - d] : 0;
    __syncthreads();
    sm[t] += v;
    __syncthreads();
  }
  int run = blockbase + sm[t] - s;
#pragma unroll
  for (int j = 0; j < 8; j++) {
    int i = base + j;
    if (i < n) { a[i] = run; run += vals[j]; }
  }
}

__global__ __launch_bounds__(256)
void rs_scatter8_k(const int* __restrict__ keyIn, const int* __restrict__ payIn,
                   int* __restrict__ keyOut, int* __restrict__ payOut,
                   const int* __restrict__ gh, int E, int shift, int nblk) {
  __shared__ int base[256];
  __shared__ int wcnt[4][256];
  int t = threadIdx.x, b = blockIdx.x;
  int w = t >> 6, ln = t & 63;
  unsigned long long lmask = (1ull << ln) - 1ull;
  base[t] = gh[t * nblk + b];
  wcnt[0][t] = 0; wcnt[1][t] = 0; wcnt[2][t] = 0; wcnt[3][t] = 0;
  __syncthreads();
  for (int j = 0; j < 8; j++) {
    int i = b * 2048 + j * 256 + t;
    bool valid = i < E;
    int kv = valid ? keyIn[i] : 0;
    int d = (kv >> shift) & 255;
    if (valid) atomicAdd(&wcnt[w][d], 1);
    unsigned long long mm = __ballot(valid);
#pragma unroll
    for (int bit = 0; bit < 8; bit++) {
      unsigned long long bb = __ballot((d >> bit) & 1);
      mm &= ((d >> bit) & 1) ? bb : ~bb;
    }
    int myrank = __popcll(mm & lmask);
    __syncthreads();
    if (valid) {
      int wbase = 0;
      for (int w2 = 0; w2 < w; w2++) wbase += wcnt[w2][d];
      int pos = base[d] + wbase + myrank;
      keyOut[pos] = kv;
      payOut[pos] = payIn ? payIn[i] : i;
    }
    __syncthreads();
    base[t] += wcnt[0][t] + wcnt[1][t] + wcnt[2][t] + wcnt[3][t];
    wcnt[0][t] = 0; wcnt[1][t] = 0; wcnt[2][t] = 0; wcnt[3][t] = 0;
    __syncthreads();
  }
}

// merged: srcP gather + CSR bounds from sorted keys
__global__ __launch_bounds__(256)
void boundsmeta_k(const int* __restrict__ key, const int* __restrict__ pay,
                  const int* __restrict__ src, int* __restrict__ off,
                  int* __restrict__ srcP, int E, int N) {
  int i = blockIdx.x * 256 + threadIdx.x;
  if (i >= E) return;
  srcP[i] = src[pay[i]];
  int k1 = key[i];
  int k0 = (i == 0) ? -1 : key[i - 1];
  for (int d = k0 + 1; d <= k1; d++) off[d] = i;
  if (i == E - 1) {
    for (int d = k1 + 1; d <= N; d++) off[d] = E;
  }
}

// ---------------- fused edge pass: exp2(q.k) -> unnorm agg + psum ----------
// wave = node; 4 edges x 16 lanes; lane q owns dims [q*8, q*8+8) (16B).
// 4 edges in flight (8 outstanding uint4 loads/lane).
__global__ __launch_bounds__(256)
void edgefuse_k(const unsigned short* __restrict__ QKV,
                const int* __restrict__ srcP, const int* __restrict__ off,
                float* __restrict__ AGu, float* __restrict__ psum,
                int Nn, float kscale) {
  __shared__ float ps[4][4];
  int t = threadIdx.x;
  int wv = t >> 6, l = t & 63;
  int p = l >> 4;                  // edge parity 0..3
  int q = l & 15;                  // 16B chunk; dims [q*8, q*8+8)
  int h = q >> 2;                  // head
  int node = blockIdx.x * 4 + wv;
  float a0 = 0.f, a1 = 0.f, a2 = 0.f, a3 = 0.f;
  float a4 = 0.f, a5 = 0.f, a6 = 0.f, a7 = 0.f;
  float pacc = 0.f;
  if (node < Nn) {
    uint4 qv = *(const uint4*)(QKV + (size_t)node * 384 + q * 8);
    int lo = off[node], hi = off[node + 1];
    int i = lo + p;
    for (; i + 12 < hi; i += 16) {
      int s0 = srcP[i], s1 = srcP[i + 4], s2 = srcP[i + 8], s3 = srcP[i + 12];
      const unsigned short* r0 = QKV + (size_t)s0 * 384;
      const unsigned short* r1 = QKV + (size_t)s1 * 384;
      const unsigned short* r2 = QKV + (size_t)s2 * 384;
      const unsigned short* r3 = QKV + (size_t)s3 * 384;
      uint4 k0 = *(const uint4*)(r0 + 128 + q * 8);
      uint4 k1 = *(const uint4*)(r1 + 128 + q * 8);
      uint4 k2 = *(const uint4*)(r2 + 128 + q * 8);
      uint4 k3 = *(const uint4*)(r3 + 128 + q * 8);
      uint4 v0 = *(const uint4*)(r0 + 256 + q * 8);
      uint4 v1 = *(const uint4*)(r1 + 256 + q * 8);
      uint4 v2 = *(const uint4*)(r2 + 256 + q * 8);
      uint4 v3 = *(const uint4*)(r3 + 256 + q * 8);
      float d0 = dot8(qv, k0);
      float d1 = dot8(qv, k1);
      float d2 = dot8(qv, k2);
      float d3 = dot8(qv, k3);
      d0 += __shfl_xor(d0, 1); d0 += __shfl_xor(d0, 2);
      d1 += __shfl_xor(d1, 1); d1 += __shfl_xor(d1, 2);
      d2 += __shfl_xor(d2, 1); d2 += __shfl_xor(d2, 2);
      d3 += __shfl_xor(d3, 1); d3 += __shfl_xor(d3, 2);
      float c0 = __builtin_amdgcn_exp2f(d0 * kscale);
      float c1 = __builtin_amdgcn_exp2f(d1 * kscale);
      float c2 = __builtin_amdgcn_exp2f(d2 * kscale);
      float c3 = __builtin_amdgcn_exp2f(d3 * kscale);
      if ((q & 3) == 0) pacc += (c0 + c1) + (c2 + c3);
      a0 = fmaf(c0, bflo(v0.x), a0); a1 = fmaf(c0, bfhi(v0.x), a1);
      a2 = fmaf(c0, bflo(v0.y), a2); a3 = fmaf(c0, bfhi(v0.y), a3);
      a4 = fmaf(c0, bflo(v0.z), a4); a5 = fmaf(c0, bfhi(v0.z), a5);
      a6 = fmaf(c0, bflo(v0.w), a6); a7 = fmaf(c0, bfhi(v0.w), a7);
      a0 = fmaf(c1, bflo(v1.x), a0); a1 = fmaf(c1, bfhi(v1.x), a1);
      a2 = fmaf(c1, bflo(v1.y), a2); a3 = fmaf(c1, bfhi(v1.y), a3);
      a4 = fmaf(c1, bflo(v1.z), a4); a5 = fmaf(c1, bfhi(v1.z), a5);
      a6 = fmaf(c1, bflo(v1.w), a6); a7 = fmaf(c1, bfhi(v1.w), a7);
      a0 = fmaf(c2, bflo(v2.x), a0); a1 = fmaf(c2, bfhi(v2.x), a1);
      a2 = fmaf(c2, bflo(v2.y), a2); a3 = fmaf(c2, bfhi(v2.y), a3);
      a4 = fmaf(c2, bflo(v2.z), a4); a5 = fmaf(c2, bfhi(v2.z), a5);
      a6 = fmaf(c2, bflo(v2.w), a6); a7 = fmaf(c2, bfhi(v2.w), a7);
      a0 = fmaf(c3, bflo(v3.x), a0); a1 = fmaf(c3, bfhi(v3.x), a1);
      a2 = fmaf(c3, bflo(v3.y), a2); a3 = fmaf(c3, bfhi(v3.y), a3);
      a4 = fmaf(c3, bflo(v3.z), a4); a5 = fmaf(c3, bfhi(v3.z), a5);
      a6 = fmaf(c3, bflo(v3.w), a6); a7 = fmaf(c3, bfhi(v3.w), a7);
    }
    for (; i < hi; i += 4) {
      int s = srcP[i];
      const unsigned short* r = QKV + (size_t)s * 384;
      uint4 kf = *(const uint4*)(r + 128 + q * 8);
      uint4 vf = *(const uint4*)(r + 256 + q * 8);
      float d = dot8(qv, kf);
      d += __shfl_xor(d, 1); d += __shfl_xor(d, 2);
      float c = __builtin_amdgcn_exp2f(d * kscale);
      if ((q & 3) == 0) pacc += c;
      a0 = fmaf(c, bflo(vf.x), a0); a1 = fmaf(c, bfhi(vf.x), a1);
      a2 = fmaf(c, bflo(vf.y), a2); a3 = fmaf(c, bfhi(vf.y), a3);
      a4 = fmaf(c, bflo(vf.z), a4); a5 = fmaf(c, bfhi(vf.z), a5);
      a6 = fmaf(c, bflo(vf.w), a6); a7 = fmaf(c, bfhi(vf.w), a7);
    }
  }
  a0 += __shfl_down(a0, 32); a0 += __shfl_down(a0, 16);
  a1 += __shfl_down(a1, 32); a1 += __shfl_down(a1, 16);
  a2 += __shfl_down(a2, 32); a2 += __shfl_down(a2, 16);
  a3 += __shfl_down(a3, 32); a3 += __shfl_down(a3, 16);
  a4 += __shfl_down(a4, 32); a4 += __shfl_down(a4, 16);
  a5 += __shfl_down(a5, 32); a5 += __shfl_down(a5, 16);
  a6 += __shfl_down(a6, 32); a6 += __shfl_down(a6, 16);
  a7 += __shfl_down(a7, 32); a7 += __shfl_down(a7, 16);
  pacc += __shfl_down(pacc, 32); pacc += __shfl_down(pacc, 16);
  if (p == 0 && (q & 3) == 0) ps[wv][h] = pacc;
  __syncthreads();
  if (t < 4) psum[(size_t)t * gridDim.x + blockIdx.x] =
      ps[0][t] + ps[1][t] + ps[2][t] + ps[3][t];
  if (node < Nn && p == 0) {
    float* op = AGu + (size_t)node * 128 + q * 8;
    *(float4*)op = make_float4(a0, a1, a2, a3);
    *(float4*)(op + 4) = make_float4(a4, a5, a6, a7);
  }
}

__global__ __launch_bounds__(256)
void reduceIz_k(const float* __restrict__ psum, float* __restrict__ iz, int nb) {
  __shared__ float sm[256];
  int h = blockIdx.x, t = threadIdx.x;
  float a = 0.f;
  for (int j = t; j < nb; j += 256) a += psum[(size_t)h * nb + j];
  sm[t] = a; __syncthreads();
  for (int s = 128; s >= 1; s >>= 1) {
    if (t < s) sm[t] += sm[t + s];
    __syncthreads();
  }
  if (t == 0) iz[h] = 1.0f / sm[0];
}

// ---------------------------------------------------------------------------
extern "C" void kernel_launch(void* const* d_in, const int* in_sizes, int n_in,
                              void* d_out, int out_size, void* d_ws, size_t ws_size,
                              hipStream_t stream) {
  const float* x_in = (const float*)d_in[0];
  const int*   ei   = (const int*)d_in[1];
  const float* Wi = (const float*)d_in[2];
  const float* bi = (const float*)d_in[3];
  const float* Wq = (const float*)d_in[4];  const float* bq = (const float*)d_in[5];
  const float* Wk = (const float*)d_in[6];  const float* bk = (const float*)d_in[7];
  const float* Wv = (const float*)d_in[8];  const float* bv = (const float*)d_in[9];
  const float* Wo = (const float*)d_in[10]; const float* bo = (const float*)d_in[11];
  const float* W1 = (const float*)d_in[12]; const float* b1 = (const float*)d_in[13];
  const float* W2 = (const float*)d_in[14]; const float* b2 = (const float*)d_in[15];

  const int N = in_sizes[0] / 128;   // 50000
  const int E = in_sizes[1] / 2;     // 800000
  const int* src = ei;
  const int* dst = ei + E;

  char* w = (char*)d_ws;
  auto alloc = [&](size_t bytes) -> char* {
    char* p = w;
    w += (bytes + 255) & ~(size_t)255;
    return p;
  };
  float*          X    = (float*)alloc((size_t)N * 128 * 4);
  unsigned short* Xb   = (unsigned short*)alloc((size_t)N * 128 * 2);
  unsigned short* QKVb = (unsigned short*)alloc((size_t)N * 384 * 2);
  unsigned short* Hb   = QKVb;                 // FFN hidden aliases QKV (dead)
  float*          AGu  = (float*)alloc((size_t)N * 128 * 4);
  const int nbS = (N + 3) / 4;                 // 12500 edgefuse blocks
  float* psum = (float*)alloc((size_t)4 * nbS * 4);
  float* iz   = (float*)alloc(16);
  unsigned short* WiT   = (unsigned short*)alloc(16384 * 2);
  unsigned short* WqkvT = (unsigned short*)alloc((size_t)2 * 384 * 128 * 2);
  unsigned short* WoT   = (unsigned short*)alloc((size_t)2 * 16384 * 2);
  unsigned short* W1T   = (unsigned short*)alloc((size_t)2 * 32768 * 2);
  unsigned short* W2T   = (unsigned short*)alloc((size_t)2 * 32768 * 2);
  float* bqkv = (float*)alloc(768 * 4);
  int* off  = (int*)alloc((size_t)(N + 1) * 4);
  int* kA   = (int*)alloc((size_t)E * 4);
  int* pA   = (int*)alloc((size_t)E * 4);
  int* kB   = (int*)alloc((size_t)E * 4);
  int* pB   = (int*)alloc((size_t)E * 4);
  int* srcP = (int*)alloc((size_t)E * 4);
  const int nblk = (E + 2047) / 2048;       // 391
  const int ghn  = 256 * nblk;              // 100096
  int* gh   = (int*)alloc((size_t)ghn * 4);
  int* bsum = (int*)alloc(256 * 4);

  const float scale = 0.17677669529663687f;           // 1/sqrt(32)
  const float kscale = scale * 1.4426950408889634f;   // fold log2(e) for exp2
  dim3 blk(256);
  const int gx = (N + 63) / 64;              // 782
  dim3 gP(gx, 2), gQKV(gx, 6), gW1(gx, 4);
  const int gEe = (E + 255) / 256;
  const int nsb = (ghn + 2047) / 2048;       // 49

  // ---- CSR build: 2-pass 8-bit stable radix sort on dst ----
  rs_hist8_k<<<nblk, blk, 0, stream>>>(dst, gh, E, 0, nblk);
  scanA_k<<<nsb, blk, 0, stream>>>(gh, bsum, ghn);
  scanC_k<<<nsb, blk, 0, stream>>>(gh, bsum, ghn);
  rs_scatter8_k<<<nblk, blk, 0, stream>>>(dst, nullptr, kA, pA, gh, E, 0, nblk);
  rs_hist8_k<<<nblk, blk, 0, stream>>>(kA, gh, E, 8, nblk);
  scanA_k<<<nsb, blk, 0, stream>>>(gh, bsum, ghn);
  scanC_k<<<nsb, blk, 0, stream>>>(gh, bsum, ghn);
  rs_scatter8_k<<<nblk, blk, 0, stream>>>(kA, pA, kB, pB, gh, E, 8, nblk);
  boundsmeta_k<<<gEe, blk, 0, stream>>>(kB, pB, src, off, srcP, E, N);

  // ---- weight prep: single fused kernel ----
  prep_k<<<1091, blk, 0, stream>>>(Wi, Wq, Wk, Wv, Wo, W1, W2, bq, bk, bv,
                                   WiT, WqkvT, WoT, W1T, W2T, bqkv);

  // ---- input projection (f32 A, cast fused into staging) ----
  mgemm_k<false, false, true, true, true, false><<<gP, blk, 0, stream>>>(
      x_in, WiT, bi, nullptr, nullptr, X, Xb, N, 128, 128);

  for (int l = 0; l < 2; l++) {
    const float* bo_l = bo + l * 128;
    const float* b1_l = b1 + l * 256;
    const float* b2_l = b2 + l * 128;

    // QKV fused GEMM -> plain row-major [node][384] (Q|K|V)
    mgemm_k<false, false, false, true, false, false><<<gQKV, blk, 0, stream>>>(
        Xb, WqkvT + (size_t)l * 384 * 128, bqkv + l * 384, nullptr, nullptr,
        nullptr, QKVb, N, 128, 384);

    // fused edge pass: unnormalized agg + per-head Z partials
    edgefuse_k<<<nbS, blk, 0, stream>>>(QKVb, srcP, off, AGu, psum, N, kscale);
    reduceIz_k<<<4, blk, 0, stream>>>(psum, iz, nbS);

    // x = x + (AGu * iz) @ Wo + bo   (scale folded into A-staging)
    mgemm_k<false, true, true, true, true, true><<<gP, blk, 0, stream>>>(
        AGu, WoT + (size_t)l * 16384, bo_l, X, iz, X, Xb, N, 128, 128);
    // h = relu(x@W1 + b1)
    mgemm_k<true, false, false, true, false, false><<<gW1, blk, 0, stream>>>(
        Xb, W1T + (size_t)l * 32768, b1_l, nullptr, nullptr, nullptr, Hb, N, 128, 256);
    // x = x + h@W2 + b2
    if (l == 0) {
      mgemm_k<false, true, true, true, false, false><<<gP, blk, 0, stream>>>(
          Hb, W2T + (size_t)l * 32768, b2_l, X, nullptr, X, Xb, N, 256, 128);
    } else {
      mgemm_k<false, true, true, false, false, false><<<gP, blk, 0, stream>>>(
          Hb, W2T + (size_t)l * 32768, b2_l, X, nullptr, (float*)d_out, nullptr, N, 256, 128);
    }
  }
}

// Round 20
// 416.281 us; speedup vs baseline: 7.6151x; 1.0187x over previous
//
#include <hip/hip_runtime.h>

// ---------------------------------------------------------------------------
// GraphTransformer R20: exact R17 restoration (best, 417us). R19's 4-edge
// ILP regressed (VGPR 48 -> occupancy 47%; TLP > ILP for latency-bound
// gathers — same lesson as R9). Edgefuse: 2 edges x 16 lanes, 36 VGPR.
// ---------------------------------------------------------------------------

typedef __attribute__((ext_vector_type(8))) short bf16x8;
typedef __attribute__((ext_vector_type(4))) float f32x4;

__device__ __forceinline__ unsigned short f2bf_rne(float f) {
  unsigned int u = __builtin_bit_cast(unsigned int, f);
  u = (u + 0x7fffu + ((u >> 16) & 1u)) >> 16;
  return (unsigned short)u;
}
__device__ __forceinline__ unsigned int pack2bf(float a, float b) {
  return (unsigned int)f2bf_rne(a) | ((unsigned int)f2bf_rne(b) << 16);
}
__device__ __forceinline__ float bflo(unsigned int w) {
  return __builtin_bit_cast(float, w << 16);
}
__device__ __forceinline__ float bfhi(unsigned int w) {
  return __builtin_bit_cast(float, w & 0xffff0000u);
}
__device__ __forceinline__ float dot8(uint4 a, uint4 b) {
  float s = bflo(a.x) * bflo(b.x) + bfhi(a.x) * bfhi(b.x);
  s += bflo(a.y) * bflo(b.y) + bfhi(a.y) * bfhi(b.y);
  s += bflo(a.z) * bflo(b.z) + bfhi(a.z) * bfhi(b.z);
  s += bflo(a.w) * bflo(b.w) + bfhi(a.w) * bfhi(b.w);
  return s;
}
__device__ __forceinline__ void gload16(const void* g, void* l) {
  __builtin_amdgcn_global_load_lds(
      (const __attribute__((address_space(1))) void*)g,
      (__attribute__((address_space(3))) void*)l, 16, 0, 0);
}

// ---------------- MFMA GEMM: Y = op(A[M,K] @ W + bias) (+R) ----------------
template<bool RELU, bool RES, bool OUTF, bool OUTB, bool AF32, bool SCALE>
__global__ __launch_bounds__(256)
void mgemm_k(const void* __restrict__ Ain,
             const unsigned short* __restrict__ Bt,
             const float* __restrict__ bias, const float* __restrict__ R,
             const float* __restrict__ scl,
             float* __restrict__ Yf, unsigned short* __restrict__ Yb,
             int M, int K, int N) {
  __shared__ __align__(16) char smem[32768];   // A 16KB | B 16KB
  const int t = threadIdx.x;
  const int l = t & 63;
  const int w = t >> 6, wm = w >> 1, wn = w & 1;
  const int row0 = blockIdx.x * 64;
  const int col0 = blockIdx.y * 64;

  f32x4 acc[2][2];
#pragma unroll
  for (int m = 0; m < 2; m++)
#pragma unroll
    for (int n = 0; n < 2; n++)
#pragma unroll
      for (int r = 0; r < 4; r++) acc[m][n][r] = 0.f;

  for (int kc = 0; kc < K; kc += 128) {
    if (kc) __syncthreads();
#pragma unroll
    for (int j = 0; j < 4; j++) {
      int id = j * 256 + t;
      int row = id >> 4, c16 = id & 15;
      int gr = row0 + row; if (gr >= M) gr = M - 1;
      if (AF32) {
        const float* ap = (const float*)Ain + (size_t)gr * K + kc + c16 * 8;
        float4 f0 = *(const float4*)ap;
        float4 f1 = *(const float4*)(ap + 4);
        float s = SCALE ? scl[(kc + c16 * 8) >> 5] : 1.f;
        uint4 val;
        val.x = pack2bf(f0.x * s, f0.y * s); val.y = pack2bf(f0.z * s, f0.w * s);
        val.z = pack2bf(f1.x * s, f1.y * s); val.w = pack2bf(f1.z * s, f1.w * s);
        *(uint4*)(smem + row * 256 + ((c16 * 16) ^ ((row & 7) << 4))) = val;
      } else {
        int sc16 = c16 ^ (row & 7);      // source-side swizzle
        const unsigned short* gp = (const unsigned short*)Ain + (size_t)gr * K + kc + sc16 * 8;
        gload16(gp, smem + (j * 256 + w * 64) * 16);
      }
    }
#pragma unroll
    for (int j = 0; j < 4; j++) {
      int id = j * 256 + t;
      int row = id >> 4, c16 = id & 15;
      int sc16 = c16 ^ (row & 7);        // source-side swizzle
      const unsigned short* gp = Bt + (size_t)(col0 + row) * K + kc + sc16 * 8;
      gload16(gp, smem + 16384 + (j * 256 + w * 64) * 16);
    }
    __syncthreads();

#pragma unroll
    for (int ks = 0; ks < 4; ks++) {
      const int bofs = ks * 64 + (l >> 4) * 16;
      bf16x8 a[2], b[2];
#pragma unroll
      for (int m = 0; m < 2; m++) {
        int r = wm * 32 + m * 16 + (l & 15);
        a[m] = *(const bf16x8*)(smem + r * 256 + (bofs ^ ((r & 7) << 4)));
      }
#pragma unroll
      for (int n = 0; n < 2; n++) {
        int r = wn * 32 + n * 16 + (l & 15);
        b[n] = *(const bf16x8*)(smem + 16384 + r * 256 + (bofs ^ ((r & 7) << 4)));
      }
#pragma unroll
      for (int m = 0; m < 2; m++)
#pragma unroll
        for (int n = 0; n < 2; n++)
          acc[m][n] = __builtin_amdgcn_mfma_f32_16x16x32_bf16(a[m], b[n], acc[m][n], 0, 0, 0);
    }
  }

  const int rbase = row0 + wm * 32 + ((l >> 4) << 2);
  const int cl = l & 15;
#pragma unroll
  for (int n = 0; n < 2; n++) {
    int col = col0 + wn * 32 + n * 16 + cl;
    float bb = bias[col];
#pragma unroll
    for (int m = 0; m < 2; m++) {
      int rtile = rbase + m * 16;
#pragma unroll
      for (int r = 0; r < 4; r++) {
        int row = rtile + r;
        if (row < M) {
          float o = acc[m][n][r] + bb;
          if (RES) o += R[(size_t)row * N + col];
          if (RELU) o = fmaxf(o, 0.f);
          if (OUTF) Yf[(size_t)row * N + col] = o;
          if (OUTB) Yb[(size_t)row * N + col] = f2bf_rne(o);
        }
      }
    }
  }
}

// ---------------- fused weight prep: all transposes + bias concat ----------
__global__ __launch_bounds__(256)
void prep_k(const float* __restrict__ Wi, const float* __restrict__ Wq,
            const float* __restrict__ Wk, const float* __restrict__ Wv,
            const float* __restrict__ Wo, const float* __restrict__ W1,
            const float* __restrict__ W2, const float* __restrict__ bq,
            const float* __restrict__ bk, const float* __restrict__ bv,
            unsigned short* __restrict__ WiT, unsigned short* __restrict__ WqkvT,
            unsigned short* __restrict__ WoT, unsigned short* __restrict__ W1T,
            unsigned short* __restrict__ W2T, float* __restrict__ bqkv) {
  int o = blockIdx.x * 256 + threadIdx.x;
  if (o < 16384) {                         // Wi
    int n = o >> 7, k = o & 127;
    WiT[o] = f2bf_rne(Wi[k * 128 + n]);
    return;
  }
  o -= 16384;
  if (o < 98304) {                         // Wq|Wk|Wv, 2 layers each 128x128
    int seg = o >> 15; int r = o & 32767;
    int l = r >> 14; int rr = r & 16383;
    int n = rr >> 7, k = rr & 127;
    const float* W = (seg == 0) ? Wq : (seg == 1) ? Wk : Wv;
    WqkvT[(size_t)l * 49152 + seg * 16384 + n * 128 + k] =
        f2bf_rne(W[(size_t)l * 16384 + k * 128 + n]);
    return;
  }
  o -= 98304;
  if (o < 32768) {                         // Wo
    int l = o >> 14; int rr = o & 16383;
    int n = rr >> 7, k = rr & 127;
    WoT[(size_t)l * 16384 + n * 128 + k] = f2bf_rne(Wo[(size_t)l * 16384 + k * 128 + n]);
    return;
  }
  o -= 32768;
  if (o < 65536) {                         // W1: K=128,N=256
    int l = o >> 15; int rr = o & 32767;
    int n = rr >> 7, k = rr & 127;
    W1T[(size_t)l * 32768 + n * 128 + k] = f2bf_rne(W1[(size_t)l * 32768 + k * 256 + n]);
    return;
  }
  o -= 65536;
  if (o < 65536) {                         // W2: K=256,N=128
    int l = o >> 15; int rr = o & 32767;
    int n = rr >> 8, k = rr & 255;
    W2T[(size_t)l * 32768 + n * 256 + k] = f2bf_rne(W2[(size_t)l * 32768 + k * 128 + n]);
    return;
  }
  o -= 65536;
  if (o < 768) {                           // bqkv concat
    int l = o / 384, c = o - l * 384;
    float v = (c < 128) ? bq[l * 128 + c] : (c < 256) ? bk[l * 128 + c - 128] : bv[l * 128 + c - 256];
    bqkv[o] = v;
  }
}

// ---------------- radix sort: 2 passes x 8-bit, stable + deterministic -----
__global__ __launch_bounds__(256)
void rs_hist8_k(const int* __restrict__ key, int* __restrict__ gh,
                int E, int shift, int nblk) {
  __shared__ int h[256];
  int t = threadIdx.x, b = blockIdx.x;
  h[t] = 0;
  __syncthreads();
#pragma unroll
  for (int j = 0; j < 8; j++) {
    int i = b * 2048 + j * 256 + t;
    if (i < E) atomicAdd(&h[(key[i] >> shift) & 255], 1);
  }
  __syncthreads();
  gh[t * nblk + b] = h[t];
}

__global__ __launch_bounds__(256)
void scanA_k(const int* __restrict__ a, int* __restrict__ bsum, int n) {
  __shared__ int sm[256];
  int b = blockIdx.x, t = threadIdx.x;
  int base = b * 2048 + t * 8;
  int s = 0;
#pragma unroll
  for (int j = 0; j < 8; j++) {
    int i = base + j;
    if (i < n) s += a[i];
  }
  sm[t] = s; __syncthreads();
  for (int d = 128; d >= 1; d >>= 1) {
    if (t < d) sm[t] += sm[t + d];
    __syncthreads();
  }
  if (t == 0) bsum[b] = sm[0];
}

// scanC with fused block-base computation (bsum holds RAW block sums)
__global__ __launch_bounds__(256)
void scanC_k(int* __restrict__ a, const int* __restrict__ bsum, int n) {
  __shared__ int sm[256];
  __shared__ int blockbase;
  int b = blockIdx.x, t = threadIdx.x;
  if (t == 0) {
    int acc = 0;
    for (int b2 = 0; b2 < b; b2++) acc += bsum[b2];
    blockbase = acc;
  }
  int base = b * 2048 + t * 8;
  int vals[8];
  int s = 0;
#pragma unroll
  for (int j = 0; j < 8; j++) {
    int i = base + j;
    vals[j] = (i < n) ? a[i] : 0;
    s += vals[j];
  }
  sm[t] = s; __syncthreads();
  for (int d = 1; d < 256; d <<= 1) {
    int v = (t >= d) ? sm[t - d] : 0;
    __syncthreads();
    sm[t] += v;
    __syncthreads();
  }
  int run = blockbase + sm[t] - s;
#pragma unroll
  for (int j = 0; j < 8; j++) {
    int i = base + j;
    if (i < n) { a[i] = run; run += vals[j]; }
  }
}

__global__ __launch_bounds__(256)
void rs_scatter8_k(const int* __restrict__ keyIn, const int* __restrict__ payIn,
                   int* __restrict__ keyOut, int* __restrict__ payOut,
                   const int* __restrict__ gh, int E, int shift, int nblk) {
  __shared__ int base[256];
  __shared__ int wcnt[4][256];
  int t = threadIdx.x, b = blockIdx.x;
  int w = t >> 6, ln = t & 63;
  unsigned long long lmask = (1ull << ln) - 1ull;
  base[t] = gh[t * nblk + b];
  wcnt[0][t] = 0; wcnt[1][t] = 0; wcnt[2][t] = 0; wcnt[3][t] = 0;
  __syncthreads();
  for (int j = 0; j < 8; j++) {
    int i = b * 2048 + j * 256 + t;
    bool valid = i < E;
    int kv = valid ? keyIn[i] : 0;
    int d = (kv >> shift) & 255;
    if (valid) atomicAdd(&wcnt[w][d], 1);
    unsigned long long mm = __ballot(valid);
#pragma unroll
    for (int bit = 0; bit < 8; bit++) {
      unsigned long long bb = __ballot((d >> bit) & 1);
      mm &= ((d >> bit) & 1) ? bb : ~bb;
    }
    int myrank = __popcll(mm & lmask);
    __syncthreads();
    if (valid) {
      int wbase = 0;
      for (int w2 = 0; w2 < w; w2++) wbase += wcnt[w2][d];
      int pos = base[d] + wbase + myrank;
      keyOut[pos] = kv;
      payOut[pos] = payIn ? payIn[i] : i;
    }
    __syncthreads();
    base[t] += wcnt[0][t] + wcnt[1][t] + wcnt[2][t] + wcnt[3][t];
    wcnt[0][t] = 0; wcnt[1][t] = 0; wcnt[2][t] = 0; wcnt[3][t] = 0;
    __syncthreads();
  }
}

// merged: srcP gather + CSR bounds from sorted keys
__global__ __launch_bounds__(256)
void boundsmeta_k(const int* __restrict__ key, const int* __restrict__ pay,
                  const int* __restrict__ src, int* __restrict__ off,
                  int* __restrict__ srcP, int E, int N) {
  int i = blockIdx.x * 256 + threadIdx.x;
  if (i >= E) return;
  srcP[i] = src[pay[i]];
  int k1 = key[i];
  int k0 = (i == 0) ? -1 : key[i - 1];
  for (int d = k0 + 1; d <= k1; d++) off[d] = i;
  if (i == E - 1) {
    for (int d = k1 + 1; d <= N; d++) off[d] = E;
  }
}

// ---------------- fused edge pass: exp2(q.k * kscale) -> unnorm agg + psum -
// wave = node; 4 edges x 16 lanes; lane q owns dims [q*8, q*8+8) (16B).
// 2 edges in flight per parity slot (R17 body: 36 VGPR, ~65% occupancy).
__global__ __launch_bounds__(256)
void edgefuse_k(const unsigned short* __restrict__ QKV,
                const int* __restrict__ srcP, const int* __restrict__ off,
                float* __restrict__ AGu, float* __restrict__ psum,
                int Nn, float kscale) {
  __shared__ float ps[4][4];
  int t = threadIdx.x;
  int wv = t >> 6, l = t & 63;
  int p = l >> 4;                  // edge parity 0..3
  int q = l & 15;                  // 16B chunk; dims [q*8, q*8+8)
  int h = q >> 2;                  // head
  int node = blockIdx.x * 4 + wv;
  float a0 = 0.f, a1 = 0.f, a2 = 0.f, a3 = 0.f;
  float a4 = 0.f, a5 = 0.f, a6 = 0.f, a7 = 0.f;
  float pacc = 0.f;
  if (node < Nn) {
    uint4 qv = *(const uint4*)(QKV + (size_t)node * 384 + q * 8);
    int lo = off[node], hi = off[node + 1];
    int i = lo + p;
    for (; i + 4 < hi; i += 8) {
      int s0 = srcP[i], s1 = srcP[i + 4];
      const unsigned short* r0 = QKV + (size_t)s0 * 384;
      const unsigned short* r1 = QKV + (size_t)s1 * 384;
      uint4 k0 = *(const uint4*)(r0 + 128 + q * 8);
      uint4 k1 = *(const uint4*)(r1 + 128 + q * 8);
      uint4 v0 = *(const uint4*)(r0 + 256 + q * 8);
      uint4 v1 = *(const uint4*)(r1 + 256 + q * 8);
      float d0 = dot8(qv, k0);
      float d1 = dot8(qv, k1);
      d0 += __shfl_xor(d0, 1); d0 += __shfl_xor(d0, 2);
      d1 += __shfl_xor(d1, 1); d1 += __shfl_xor(d1, 2);
      float c0 = __builtin_amdgcn_exp2f(d0 * kscale);
      float c1 = __builtin_amdgcn_exp2f(d1 * kscale);
      if ((q & 3) == 0) pacc += c0 + c1;
      a0 = fmaf(c0, bflo(v0.x), a0); a1 = fmaf(c0, bfhi(v0.x), a1);
      a2 = fmaf(c0, bflo(v0.y), a2); a3 = fmaf(c0, bfhi(v0.y), a3);
      a4 = fmaf(c0, bflo(v0.z), a4); a5 = fmaf(c0, bfhi(v0.z), a5);
      a6 = fmaf(c0, bflo(v0.w), a6); a7 = fmaf(c0, bfhi(v0.w), a7);
      a0 = fmaf(c1, bflo(v1.x), a0); a1 = fmaf(c1, bfhi(v1.x), a1);
      a2 = fmaf(c1, bflo(v1.y), a2); a3 = fmaf(c1, bfhi(v1.y), a3);
      a4 = fmaf(c1, bflo(v1.z), a4); a5 = fmaf(c1, bfhi(v1.z), a5);
      a6 = fmaf(c1, bflo(v1.w), a6); a7 = fmaf(c1, bfhi(v1.w), a7);
    }
    for (; i < hi; i += 4) {
      int s = srcP[i];
      const unsigned short* r = QKV + (size_t)s * 384;
      uint4 kf = *(const uint4*)(r + 128 + q * 8);
      uint4 vf = *(const uint4*)(r + 256 + q * 8);
      float d = dot8(qv, kf);
      d += __shfl_xor(d, 1); d += __shfl_xor(d, 2);
      float c = __builtin_amdgcn_exp2f(d * kscale);
      if ((q & 3) == 0) pacc += c;
      a0 = fmaf(c, bflo(vf.x), a0); a1 = fmaf(c, bfhi(vf.x), a1);
      a2 = fmaf(c, bflo(vf.y), a2); a3 = fmaf(c, bfhi(vf.y), a3);
      a4 = fmaf(c, bflo(vf.z), a4); a5 = fmaf(c, bfhi(vf.z), a5);
      a6 = fmaf(c, bflo(vf.w), a6); a7 = fmaf(c, bfhi(vf.w), a7);
    }
  }
  a0 += __shfl_down(a0, 32); a0 += __shfl_down(a0, 16);
  a1 += __shfl_down(a1, 32); a1 += __shfl_down(a1, 16);
  a2 += __shfl_down(a2, 32); a2 += __shfl_down(a2, 16);
  a3 += __shfl_down(a3, 32); a3 += __shfl_down(a3, 16);
  a4 += __shfl_down(a4, 32); a4 += __shfl_down(a4, 16);
  a5 += __shfl_down(a5, 32); a5 += __shfl_down(a5, 16);
  a6 += __shfl_down(a6, 32); a6 += __shfl_down(a6, 16);
  a7 += __shfl_down(a7, 32); a7 += __shfl_down(a7, 16);
  pacc += __shfl_down(pacc, 32); pacc += __shfl_down(pacc, 16);
  if (p == 0 && (q & 3) == 0) ps[wv][h] = pacc;
  __syncthreads();
  if (t < 4) psum[(size_t)t * gridDim.x + blockIdx.x] =
      ps[0][t] + ps[1][t] + ps[2][t] + ps[3][t];
  if (node < Nn && p == 0) {
    float* op = AGu + (size_t)node * 128 + q * 8;
    *(float4*)op = make_float4(a0, a1, a2, a3);
    *(float4*)(op + 4) = make_float4(a4, a5, a6, a7);
  }
}

__global__ __launch_bounds__(256)
void reduceIz_k(const float* __restrict__ psum, float* __restrict__ iz, int nb) {
  __shared__ float sm[256];
  int h = blockIdx.x, t = threadIdx.x;
  float a = 0.f;
  for (int j = t; j < nb; j += 256) a += psum[(size_t)h * nb + j];
  sm[t] = a; __syncthreads();
  for (int s = 128; s >= 1; s >>= 1) {
    if (t < s) sm[t] += sm[t + s];
    __syncthreads();
  }
  if (t == 0) iz[h] = 1.0f / sm[0];
}

// ---------------------------------------------------------------------------
extern "C" void kernel_launch(void* const* d_in, const int* in_sizes, int n_in,
                              void* d_out, int out_size, void* d_ws, size_t ws_size,
                              hipStream_t stream) {
  const float* x_in = (const float*)d_in[0];
  const int*   ei   = (const int*)d_in[1];
  const float* Wi = (const float*)d_in[2];
  const float* bi = (const float*)d_in[3];
  const float* Wq = (const float*)d_in[4];  const float* bq = (const float*)d_in[5];
  const float* Wk = (const float*)d_in[6];  const float* bk = (const float*)d_in[7];
  const float* Wv = (const float*)d_in[8];  const float* bv = (const float*)d_in[9];
  const float* Wo = (const float*)d_in[10]; const float* bo = (const float*)d_in[11];
  const float* W1 = (const float*)d_in[12]; const float* b1 = (const float*)d_in[13];
  const float* W2 = (const float*)d_in[14]; const float* b2 = (const float*)d_in[15];

  const int N = in_sizes[0] / 128;   // 50000
  const int E = in_sizes[1] / 2;     // 800000
  const int* src = ei;
  const int* dst = ei + E;

  char* w = (char*)d_ws;
  auto alloc = [&](size_t bytes) -> char* {
    char* p = w;
    w += (bytes + 255) & ~(size_t)255;
    return p;
  };
  float*          X    = (float*)alloc((size_t)N * 128 * 4);
  unsigned short* Xb   = (unsigned short*)alloc((size_t)N * 128 * 2);
  unsigned short* QKVb = (unsigned short*)alloc((size_t)N * 384 * 2);
  unsigned short* Hb   = QKVb;                 // FFN hidden aliases QKV (dead)
  float*          AGu  = (float*)alloc((size_t)N * 128 * 4);
  const int nbS = (N + 3) / 4;                 // 12500 edgefuse blocks
  float* psum = (float*)alloc((size_t)4 * nbS * 4);
  float* iz   = (float*)alloc(16);
  unsigned short* WiT   = (unsigned short*)alloc(16384 * 2);
  unsigned short* WqkvT = (unsigned short*)alloc((size_t)2 * 384 * 128 * 2);
  unsigned short* WoT   = (unsigned short*)alloc((size_t)2 * 16384 * 2);
  unsigned short* W1T   = (unsigned short*)alloc((size_t)2 * 32768 * 2);
  unsigned short* W2T   = (unsigned short*)alloc((size_t)2 * 32768 * 2);
  float* bqkv = (float*)alloc(768 * 4);
  int* off  = (int*)alloc((size_t)(N + 1) * 4);
  int* kA   = (int*)alloc((size_t)E * 4);
  int* pA   = (int*)alloc((size_t)E * 4);
  int* kB   = (int*)alloc((size_t)E * 4);
  int* pB   = (int*)alloc((size_t)E * 4);
  int* srcP = (int*)alloc((size_t)E * 4);
  const int nblk = (E + 2047) / 2048;       // 391
  const int ghn  = 256 * nblk;              // 100096
  int* gh   = (int*)alloc((size_t)ghn * 4);
  int* bsum = (int*)alloc(256 * 4);

  const float scale = 0.17677669529663687f;           // 1/sqrt(32)
  const float kscale = scale * 1.4426950408889634f;   // fold log2(e) for exp2
  dim3 blk(256);
  const int gx = (N + 63) / 64;              // 782
  dim3 gP(gx, 2), gQKV(gx, 6), gW1(gx, 4);
  const int gEe = (E + 255) / 256;
  const int nsb = (ghn + 2047) / 2048;       // 49

  // ---- CSR build: 2-pass 8-bit stable radix sort on dst ----
  rs_hist8_k<<<nblk, blk, 0, stream>>>(dst, gh, E, 0, nblk);
  scanA_k<<<nsb, blk, 0, stream>>>(gh, bsum, ghn);
  scanC_k<<<nsb, blk, 0, stream>>>(gh, bsum, ghn);
  rs_scatter8_k<<<nblk, blk, 0, stream>>>(dst, nullptr, kA, pA, gh, E, 0, nblk);
  rs_hist8_k<<<nblk, blk, 0, stream>>>(kA, gh, E, 8, nblk);
  scanA_k<<<nsb, blk, 0, stream>>>(gh, bsum, ghn);
  scanC_k<<<nsb, blk, 0, stream>>>(gh, bsum, ghn);
  rs_scatter8_k<<<nblk, blk, 0, stream>>>(kA, pA, kB, pB, gh, E, 8, nblk);
  boundsmeta_k<<<gEe, blk, 0, stream>>>(kB, pB, src, off, srcP, E, N);

  // ---- weight prep: single fused kernel ----
  prep_k<<<1091, blk, 0, stream>>>(Wi, Wq, Wk, Wv, Wo, W1, W2, bq, bk, bv,
                                   WiT, WqkvT, WoT, W1T, W2T, bqkv);

  // ---- input projection (f32 A, cast fused into staging) ----
  mgemm_k<false, false, true, true, true, false><<<gP, blk, 0, stream>>>(
      x_in, WiT, bi, nullptr, nullptr, X, Xb, N, 128, 128);

  for (int l = 0; l < 2; l++) {
    const float* bo_l = bo + l * 128;
    const float* b1_l = b1 + l * 256;
    const float* b2_l = b2 + l * 128;

    // QKV fused GEMM -> plain row-major [node][384] (Q|K|V)
    mgemm_k<false, false, false, true, false, false><<<gQKV, blk, 0, stream>>>(
        Xb, WqkvT + (size_t)l * 384 * 128, bqkv + l * 384, nullptr, nullptr,
        nullptr, QKVb, N, 128, 384);

    // fused edge pass: unnormalized agg + per-head Z partials
    edgefuse_k<<<nbS, blk, 0, stream>>>(QKVb, srcP, off, AGu, psum, N, kscale);
    reduceIz_k<<<4, blk, 0, stream>>>(psum, iz, nbS);

    // x = x + (AGu * iz) @ Wo + bo   (scale folded into A-staging)
    mgemm_k<false, true, true, true, true, true><<<gP, blk, 0, stream>>>(
        AGu, WoT + (size_t)l * 16384, bo_l, X, iz, X, Xb, N, 128, 128);
    // h = relu(x@W1 + b1)
    mgemm_k<true, false, false, true, false, false><<<gW1, blk, 0, stream>>>(
        Xb, W1T + (size_t)l * 32768, b1_l, nullptr, nullptr, nullptr, Hb, N, 128, 256);
    // x = x + h@W2 + b2
    if (l == 0) {
      mgemm_k<false, true, true, true, false, false><<<gP, blk, 0, stream>>>(
          Hb, W2T + (size_t)l * 32768, b2_l, X, nullptr, X, Xb, N, 256, 128);
    } else {
      mgemm_k<false, true, true, false, false, false><<<gP, blk, 0, stream>>>(
          Hb, W2T + (size_t)l * 32768, b2_l, X, nullptr, (float*)d_out, nullptr, N, 256, 128);
    }
  }
}